// Round 1
// baseline (531.682 us; speedup 1.0000x reference)
//
#include <hip/hip_runtime.h>

#define NN   32768
#define HD   128
#define EE   524288
#define GG   256
#define NPGd 128
#define CCd  16
#define LLd  3

// ---------------- CSR build (once per call; ws re-poisoned every launch) ----------------
__global__ __launch_bounds__(256) void count_kernel(const int* __restrict__ tgt, int* __restrict__ deg) {
  int e = blockIdx.x * 256 + threadIdx.x;
  if (e < EE) atomicAdd(&deg[tgt[e]], 1);
}

__global__ __launch_bounds__(1024) void scan_kernel(const int* __restrict__ deg, int* __restrict__ offs) {
  __shared__ int part[1024];
  int tid = threadIdx.x;
  int base = tid * 32;
  int local[32];
  int s = 0;
#pragma unroll
  for (int k = 0; k < 32; ++k) { local[k] = deg[base + k]; s += local[k]; }
  part[tid] = s;
  __syncthreads();
  for (int off = 1; off < 1024; off <<= 1) {
    int v = part[tid];
    int add = (tid >= off) ? part[tid - off] : 0;
    __syncthreads();
    part[tid] = v + add;
    __syncthreads();
  }
  int run = (tid == 0) ? 0 : part[tid - 1];
#pragma unroll
  for (int k = 0; k < 32; ++k) { offs[base + k] = run; run += local[k]; }
  if (tid == 1023) offs[NN] = run;
}

__global__ __launch_bounds__(256) void scatter_kernel(const int* __restrict__ src, const int* __restrict__ tgt,
                                                      const int* __restrict__ mask, const int* __restrict__ offs,
                                                      int* __restrict__ fill, int* __restrict__ csr) {
  int e = blockIdx.x * 256 + threadIdx.x;
  if (e >= EE) return;
  int t = tgt[e];
  int p = offs[t] + atomicAdd(&fill[t], 1);
  int enc = src[e];
  if (mask[e] != 0) enc |= (int)0x80000000;  // sign bit = "mask break" -> Wn path
  csr[p] = enc;
}

// ---------------- per-layer: aggregate neighbors (mean-scaled) ----------------
// A_in[t] = inv_cnt * sum_{mask edges} h[src], A_out likewise; fin/fout = cnt_in*inv, cnt_out*inv
__global__ __launch_bounds__(128) void agg_kernel(const float* __restrict__ h, const int* __restrict__ offs,
                                                  const int* __restrict__ csr,
                                                  float* __restrict__ Ain, float* __restrict__ Aout,
                                                  float* __restrict__ fin, float* __restrict__ fout) {
  const int t = blockIdx.x;
  const int tid = threadIdx.x;
  const int o0 = offs[t], o1 = offs[t + 1];
  float ain = 0.f, aout = 0.f;
  int nin = 0;
  for (int p = o0; p < o1; ++p) {
    int enc = csr[p];
    int srcn = enc & 0x7fffffff;
    float v = h[(size_t)srcn * HD + tid];
    if (enc < 0) { ain += v; ++nin; } else { aout += v; }
  }
  const int dg = o1 - o0;
  const float inv = 1.0f / (float)(dg > 0 ? dg : 1);
  Ain[(size_t)t * HD + tid] = ain * inv;
  Aout[(size_t)t * HD + tid] = aout * inv;
  if (tid == 0) { fin[t] = (float)nin * inv; fout[t] = (float)(dg - nin) * inv; }
}

// ---------------- fused GEMM (K=384: Ain|Aout|h vs Wn|Wo|Wr) + bias + LN + ReLU ----------------
// block: 256 threads = 16x16; tile 64 rows x 128 cols; micro 4x8
__global__ __launch_bounds__(256) void gemm_ln_kernel(
    const float* __restrict__ Ain, const float* __restrict__ Aout, const float* __restrict__ h,
    const float* __restrict__ Wn, const float* __restrict__ Wo, const float* __restrict__ Wr,
    const float* __restrict__ bn, const float* __restrict__ bo,
    const float* __restrict__ fin, const float* __restrict__ fout,
    const float* __restrict__ lng, const float* __restrict__ lnb,
    float* __restrict__ hout) {
  __shared__ float inT[32][64];    // [k][row]
  __shared__ float wT[32][128];    // [k][j]
  const int tid = threadIdx.x;
  const int tx = tid & 15;
  const int ty = tid >> 4;
  const int row0 = blockIdx.x * 64;
  float acc[4][8];
#pragma unroll
  for (int a = 0; a < 4; ++a)
#pragma unroll
    for (int b = 0; b < 8; ++b) acc[a][b] = 0.f;

  const float* As[3] = {Ain, Aout, h};
  const float* Wss[3] = {Wn, Wo, Wr};
  for (int seg = 0; seg < 3; ++seg) {
    const float* A = As[seg];
    const float* W = Wss[seg];
    for (int kc = 0; kc < 4; ++kc) {
      const int k0 = kc * 32;
#pragma unroll
      for (int i = 0; i < 2; ++i) {            // stage 64x32 input chunk, transposed
        int f4 = tid + i * 256;
        int r = f4 >> 3;
        int kq = (f4 & 7) << 2;
        float4 v = *(const float4*)(A + (size_t)(row0 + r) * HD + k0 + kq);
        inT[kq + 0][r] = v.x; inT[kq + 1][r] = v.y; inT[kq + 2][r] = v.z; inT[kq + 3][r] = v.w;
      }
#pragma unroll
      for (int i = 0; i < 4; ++i) {            // stage 128x32 weight chunk, transposed
        int f4 = tid + i * 256;
        int j = f4 >> 3;
        int kq = (f4 & 7) << 2;
        float4 v = *(const float4*)(W + j * HD + k0 + kq);
        wT[kq + 0][j] = v.x; wT[kq + 1][j] = v.y; wT[kq + 2][j] = v.z; wT[kq + 3][j] = v.w;
      }
      __syncthreads();
#pragma unroll
      for (int kk = 0; kk < 32; ++kk) {
        float4 a4 = *(const float4*)&inT[kk][ty << 2];
        float4 b0 = *(const float4*)&wT[kk][tx << 3];
        float4 b1 = *(const float4*)&wT[kk][(tx << 3) + 4];
        float av[4] = {a4.x, a4.y, a4.z, a4.w};
        float bv[8] = {b0.x, b0.y, b0.z, b0.w, b1.x, b1.y, b1.z, b1.w};
#pragma unroll
        for (int ii = 0; ii < 4; ++ii)
#pragma unroll
          for (int jj = 0; jj < 8; ++jj) acc[ii][jj] += av[ii] * bv[jj];
      }
      __syncthreads();
    }
  }
  // epilogue: + frac_in*bn + frac_out*bo, then LN over the 128 cols (16 lanes * 8 vals), ReLU
  const int jb = tx << 3;
  float bnv[8], bov[8], gv[8], bb[8];
#pragma unroll
  for (int jj = 0; jj < 8; ++jj) {
    bnv[jj] = bn[jb + jj];
    bov[jj] = bo[jb + jj];
    gv[jj] = lng[jb + jj];
    bb[jj] = lnb[jb + jj];
  }
#pragma unroll
  for (int ii = 0; ii < 4; ++ii) {
    int row = row0 + (ty << 2) + ii;
    float f_in = fin[row], f_out = fout[row];
    float v[8];
    float sum = 0.f;
#pragma unroll
    for (int jj = 0; jj < 8; ++jj) {
      v[jj] = acc[ii][jj] + f_in * bnv[jj] + f_out * bov[jj];
      sum += v[jj];
    }
#pragma unroll
    for (int m = 1; m < 16; m <<= 1) sum += __shfl_xor(sum, m, 64);  // 16 contiguous lanes own a row
    float mu = sum * (1.0f / 128.0f);
    float sq = 0.f;
#pragma unroll
    for (int jj = 0; jj < 8; ++jj) { float d = v[jj] - mu; sq += d * d; }
#pragma unroll
    for (int m = 1; m < 16; m <<= 1) sq += __shfl_xor(sq, m, 64);
    float rstd = rsqrtf(sq * (1.0f / 128.0f) + 1e-5f);
    float o[8];
#pragma unroll
    for (int jj = 0; jj < 8; ++jj) {
      float t2 = (v[jj] - mu) * rstd * gv[jj] + bb[jj];
      o[jj] = fmaxf(t2, 0.0f);
    }
    float4* dst = (float4*)(hout + (size_t)row * HD + jb);
    dst[0] = make_float4(o[0], o[1], o[2], o[3]);
    dst[1] = make_float4(o[4], o[5], o[6], o[7]);
  }
}

// ---------------- pooled[g,c,h] = sum_n s[g,n,c]*h[g,n,h]; colsum[g,c] = sum_n s ----------------
__global__ __launch_bounds__(256) void pool_kernel(const float* __restrict__ h, const float* __restrict__ s,
                                                   float* __restrict__ pooled, float* __restrict__ colsum) {
  __shared__ float xs[128][128];  // 64 KB
  __shared__ float ss[128][16];   // 8 KB
  const int g = blockIdx.x;
  const int tid = threadIdx.x;
  const float* hg = h + (size_t)g * NPGd * HD;
  const float* sg = s + (size_t)g * NPGd * CCd;
#pragma unroll
  for (int i = 0; i < 16; ++i) {
    int f4 = tid + i * 256;
    int n = f4 >> 5;
    int q = (f4 & 31) << 2;
    *(float4*)&xs[n][q] = *(const float4*)(hg + n * HD + q);
  }
#pragma unroll
  for (int i = 0; i < 2; ++i) {
    int f4 = tid + i * 256;
    int n = f4 >> 2;
    int q = (f4 & 3) << 2;
    *(float4*)&ss[n][q] = *(const float4*)(sg + n * CCd + q);
  }
  __syncthreads();
  const int c = tid >> 4;
  const int j0 = (tid & 15) << 3;
  float acc[8] = {0, 0, 0, 0, 0, 0, 0, 0};
  for (int n = 0; n < 128; ++n) {
    float sv = ss[n][c];
    float4 x0 = *(const float4*)&xs[n][j0];
    float4 x1 = *(const float4*)&xs[n][j0 + 4];
    acc[0] += sv * x0.x; acc[1] += sv * x0.y; acc[2] += sv * x0.z; acc[3] += sv * x0.w;
    acc[4] += sv * x1.x; acc[5] += sv * x1.y; acc[6] += sv * x1.z; acc[7] += sv * x1.w;
  }
  float* pg = pooled + ((size_t)g * CCd + c) * HD + j0;
  *(float4*)pg = make_float4(acc[0], acc[1], acc[2], acc[3]);
  *(float4*)(pg + 4) = make_float4(acc[4], acc[5], acc[6], acc[7]);
  if (tid < CCd) {
    float cs = 0.f;
    for (int n = 0; n < 128; ++n) cs += ss[n][tid];
    colsum[g * CCd + tid] = cs;
  }
}

// ---------------- final LN + lin + mask + per-graph sums; writes out[g] and xc ----------------
__global__ __launch_bounds__(256) void final_kernel(const float* __restrict__ pooled, const float* __restrict__ colsum,
                                                    const float* __restrict__ flng, const float* __restrict__ flnb,
                                                    const float* __restrict__ linw, const float* __restrict__ bias,
                                                    float* __restrict__ out, float* __restrict__ l1g) {
  const int g = blockIdx.x;
  const int tid = threadIdx.x;
  const int c = tid >> 4;
  const int j0 = (tid & 15) << 3;
  const float* row = pooled + ((size_t)g * CCd + c) * HD + j0;
  float4 r0 = *(const float4*)row;
  float4 r1 = *(const float4*)(row + 4);
  float v[8] = {r0.x, r0.y, r0.z, r0.w, r1.x, r1.y, r1.z, r1.w};
  float sum = 0.f;
#pragma unroll
  for (int jj = 0; jj < 8; ++jj) sum += v[jj];
#pragma unroll
  for (int m = 1; m < 16; m <<= 1) sum += __shfl_xor(sum, m, 64);
  float mu = sum * (1.0f / 128.0f);
  float sq = 0.f;
#pragma unroll
  for (int jj = 0; jj < 8; ++jj) { float d = v[jj] - mu; sq += d * d; }
#pragma unroll
  for (int m = 1; m < 16; m <<= 1) sq += __shfl_xor(sq, m, 64);
  float rstd = rsqrtf(sq * (1.0f / 128.0f) + 1e-5f);
  float dot = 0.f;
#pragma unroll
  for (int jj = 0; jj < 8; ++jj) {
    float nv = (v[jj] - mu) * rstd * flng[j0 + jj] + flnb[j0 + jj];
    dot += nv * linw[j0 + jj];
  }
#pragma unroll
  for (int m = 1; m < 16; m <<= 1) dot += __shfl_xor(dot, m, 64);
  __shared__ float xcs[CCd], axcs[CCd], ms[CCd];
  if ((tid & 15) == 0) {
    float cm = (colsum[g * CCd + c] > 0.f) ? 1.0f : 0.0f;
    float xcv = dot * cm;
    out[257 + g * CCd + c] = xcv;  // xc block starts after out(256) + losses(1)
    xcs[c] = xcv; axcs[c] = fabsf(xcv); ms[c] = cm;
  }
  __syncthreads();
  if (tid == 0) {
    float so = 0.f, sa = 0.f, sd = 0.f;
#pragma unroll
    for (int k = 0; k < CCd; ++k) { so += xcs[k]; sa += axcs[k]; sd += ms[k] + 1e-7f; }
    out[g] = so + bias[0];
    l1g[g] = sa / sd;
  }
}

// ---------------- losses = 0.01*(sum|Wo|+sum|bo|) + 0.01*mean_g(l1g) ----------------
__global__ __launch_bounds__(256) void loss_kernel(const float* __restrict__ Wo, const float* __restrict__ bo,
                                                   const float* __restrict__ l1g, float* __restrict__ outp) {
  const int tid = threadIdx.x;
  float s = 0.f;
  for (int i = tid; i < LLd * HD * HD; i += 256) s += fabsf(Wo[i]);
  for (int i = tid; i < LLd * HD; i += 256) s += fabsf(bo[i]);
  float s2 = (tid < GG) ? l1g[tid] : 0.f;
#pragma unroll
  for (int m = 1; m < 64; m <<= 1) { s += __shfl_xor(s, m, 64); s2 += __shfl_xor(s2, m, 64); }
  __shared__ float rs[4], rs2[4];
  int w = tid >> 6;
  if ((tid & 63) == 0) { rs[w] = s; rs2[w] = s2; }
  __syncthreads();
  if (tid == 0) {
    float reg = rs[0] + rs[1] + rs[2] + rs[3];
    float l1 = (rs2[0] + rs2[1] + rs2[2] + rs2[3]) * (1.0f / GG);
    outp[0] = 0.01f * reg + 0.01f * l1;
  }
}

extern "C" void kernel_launch(void* const* d_in, const int* in_sizes, int n_in,
                              void* d_out, int out_size, void* d_ws, size_t ws_size,
                              hipStream_t stream) {
  (void)in_sizes; (void)n_in; (void)out_size; (void)ws_size;
  const float* x    = (const float*)d_in[0];
  const int*   ei   = (const int*)d_in[1];
  const int*   mask = (const int*)d_in[2];
  const float* s    = (const float*)d_in[3];
  // d_in[4] = batch (unused: equal-size graphs, sorted)
  const float* Wn   = (const float*)d_in[5];
  const float* bn   = (const float*)d_in[6];
  const float* Wo   = (const float*)d_in[7];
  const float* bo   = (const float*)d_in[8];
  const float* Wr   = (const float*)d_in[9];
  const float* lng  = (const float*)d_in[10];
  const float* lnb  = (const float*)d_in[11];
  const float* flng = (const float*)d_in[12];
  const float* flnb = (const float*)d_in[13];
  const float* linw = (const float*)d_in[14];
  const float* bias = (const float*)d_in[15];
  float* out = (float*)d_out;

  char* ws = (char*)d_ws;
  size_t off = 0;
  auto alloc = [&](size_t b) { char* p = ws + off; off += (b + 255) & ~(size_t)255; return p; };
  int* deg     = (int*)alloc((size_t)NN * 4);
  int* offs    = (int*)alloc((size_t)(NN + 1) * 4);
  int* fill    = (int*)alloc((size_t)NN * 4);
  int* csr     = (int*)alloc((size_t)EE * 4);
  float* hA    = (float*)alloc((size_t)NN * HD * 4);
  float* hB    = (float*)alloc((size_t)NN * HD * 4);
  float* Ain   = (float*)alloc((size_t)NN * HD * 4);
  float* Aout  = (float*)alloc((size_t)NN * HD * 4);
  float* fin   = (float*)alloc((size_t)NN * 4);
  float* fout  = (float*)alloc((size_t)NN * 4);
  float* pooled= (float*)alloc((size_t)GG * CCd * HD * 4);
  float* colsum= (float*)alloc((size_t)GG * CCd * 4);
  float* l1g   = (float*)alloc((size_t)GG * 4);

  const int* srcA = ei;
  const int* tgtA = ei + EE;

  hipMemsetAsync(deg, 0, (size_t)NN * 4, stream);
  hipMemsetAsync(fill, 0, (size_t)NN * 4, stream);
  count_kernel<<<EE / 256, 256, 0, stream>>>(tgtA, deg);
  scan_kernel<<<1, 1024, 0, stream>>>(deg, offs);
  scatter_kernel<<<EE / 256, 256, 0, stream>>>(srcA, tgtA, mask, offs, fill, csr);

  const float* hcur = x;
  float* houts[3] = {hA, hB, hA};
  for (int i = 0; i < LLd; ++i) {
    agg_kernel<<<NN, 128, 0, stream>>>(hcur, offs, csr, Ain, Aout, fin, fout);
    gemm_ln_kernel<<<NN / 64, 256, 0, stream>>>(Ain, Aout, hcur,
        Wn + (size_t)i * HD * HD, Wo + (size_t)i * HD * HD, Wr + (size_t)i * HD * HD,
        bn + (size_t)i * HD, bo + (size_t)i * HD, fin, fout,
        lng + (size_t)i * HD, lnb + (size_t)i * HD, houts[i]);
    hcur = houts[i];
  }
  pool_kernel<<<GG, 256, 0, stream>>>(hcur, s, pooled, colsum);
  final_kernel<<<GG, 256, 0, stream>>>(pooled, colsum, flng, flnb, linw, bias, out, l1g);
  loss_kernel<<<1, 256, 0, stream>>>(Wo, bo, l1g, out + 256);
}

// Round 2
// 348.151 us; speedup vs baseline: 1.5272x; 1.5272x over previous
//
#include <hip/hip_runtime.h>

#define NN   32768
#define HD   128
#define EE   524288
#define GG   256
#define NPGd 128
#define CCd  16
#define LLd  3

typedef short short8 __attribute__((ext_vector_type(8)));   // 8 bf16 = 4 VGPRs
typedef float f32x4 __attribute__((ext_vector_type(4)));

__device__ __forceinline__ unsigned short f2bf(float f) {
  unsigned u = __builtin_bit_cast(unsigned, f);
  return (unsigned short)((u + 0x7FFFu + ((u >> 16) & 1u)) >> 16);  // RNE
}
__device__ __forceinline__ float bf_lo(unsigned p) { return __builtin_bit_cast(float, p << 16); }
__device__ __forceinline__ float bf_hi(unsigned p) { return __builtin_bit_cast(float, p & 0xFFFF0000u); }
__device__ __forceinline__ unsigned bfpack(float a, float b) {
  return (unsigned)f2bf(a) | ((unsigned)f2bf(b) << 16);
}

// ---------------- converts ----------------
__global__ __launch_bounds__(256) void convert_x_kernel(const float* __restrict__ x, unsigned* __restrict__ xb) {
  int i = blockIdx.x * 256 + threadIdx.x;   // handles 8 floats -> 4 uints
  const float4* src = (const float4*)(x + (size_t)i * 8);
  float4 a = src[0], b = src[1];
  uint4 o;
  o.x = bfpack(a.x, a.y); o.y = bfpack(a.z, a.w);
  o.z = bfpack(b.x, b.y); o.w = bfpack(b.z, b.w);
  *(uint4*)(xb + (size_t)i * 4) = o;
}

__global__ __launch_bounds__(256) void convert_w_kernel(const float* __restrict__ Wn, const float* __restrict__ Wo,
                                                        const float* __restrict__ Wr,
                                                        unsigned* __restrict__ Wnb, unsigned* __restrict__ Wob,
                                                        unsigned* __restrict__ Wrb) {
  int i = blockIdx.x * 256 + threadIdx.x;   // handles 4 floats -> 2 uints, per array
  float4 a = *(const float4*)(Wn + (size_t)i * 4);
  float4 b = *(const float4*)(Wo + (size_t)i * 4);
  float4 c = *(const float4*)(Wr + (size_t)i * 4);
  *(uint2*)(Wnb + (size_t)i * 2) = make_uint2(bfpack(a.x, a.y), bfpack(a.z, a.w));
  *(uint2*)(Wob + (size_t)i * 2) = make_uint2(bfpack(b.x, b.y), bfpack(b.z, b.w));
  *(uint2*)(Wrb + (size_t)i * 2) = make_uint2(bfpack(c.x, c.y), bfpack(c.z, c.w));
}

// ---------------- CSR build ----------------
__global__ __launch_bounds__(256) void count_kernel(const int* __restrict__ tgt, int* __restrict__ deg) {
  int e = blockIdx.x * 256 + threadIdx.x;
  if (e < EE) atomicAdd(&deg[tgt[e]], 1);
}

__global__ __launch_bounds__(1024) void scan_kernel(const int* __restrict__ deg, int* __restrict__ offs) {
  __shared__ int part[1024];
  int tid = threadIdx.x;
  int base = tid * 32;
  int local[32];
  int s = 0;
#pragma unroll
  for (int k = 0; k < 32; ++k) { local[k] = deg[base + k]; s += local[k]; }
  part[tid] = s;
  __syncthreads();
  for (int off = 1; off < 1024; off <<= 1) {
    int v = part[tid];
    int add = (tid >= off) ? part[tid - off] : 0;
    __syncthreads();
    part[tid] = v + add;
    __syncthreads();
  }
  int run = (tid == 0) ? 0 : part[tid - 1];
#pragma unroll
  for (int k = 0; k < 32; ++k) { offs[base + k] = run; run += local[k]; }
  if (tid == 1023) offs[NN] = run;
}

__global__ __launch_bounds__(256) void scatter_kernel(const int* __restrict__ src, const int* __restrict__ tgt,
                                                      const int* __restrict__ mask, const int* __restrict__ offs,
                                                      int* __restrict__ fill, int* __restrict__ csr) {
  int e = blockIdx.x * 256 + threadIdx.x;
  if (e >= EE) return;
  int t = tgt[e];
  int p = offs[t] + atomicAdd(&fill[t], 1);
  int enc = src[e];
  if (mask[e] != 0) enc |= (int)0x80000000;  // sign bit = "mask break" -> Wn path
  csr[p] = enc;
}

// ---------------- agg: per-graph LDS gather (bf16 h) ----------------
// grid = 4*G blocks; block b handles 32 nodes of graph g; wave handles 8 nodes.
__global__ __launch_bounds__(256) void agg_kernel(const unsigned* __restrict__ h,  // bf16x2 [NN][64]
                                                  const int* __restrict__ offs, const int* __restrict__ csr,
                                                  unsigned* __restrict__ Ain, unsigned* __restrict__ Aout,
                                                  float* __restrict__ fin, float* __restrict__ fout) {
  __shared__ unsigned hs[128 * 64];  // 32 KB: graph's h block, [node][bf16 pair]
  const int g = blockIdx.x >> 2;
  const int b = blockIdx.x & 3;
  const int tid = threadIdx.x;
  const int wave = tid >> 6, lane = tid & 63;
  const uint4* hg4 = (const uint4*)(h + (size_t)g * 128 * 64);
  uint4* hs4 = (uint4*)hs;
#pragma unroll
  for (int i = 0; i < 8; ++i) hs4[tid + i * 256] = hg4[tid + i * 256];
  __syncthreads();
#pragma unroll 1
  for (int rep = 0; rep < 8; ++rep) {
    const int t = g * 128 + b * 32 + wave * 8 + rep;
    const int o0 = offs[t], o1 = offs[t + 1];
    float ai0 = 0.f, ai1 = 0.f, ao0 = 0.f, ao1 = 0.f;
    int nin = 0;
    int p = o0;
    for (; p + 1 < o1; p += 2) {
      int e0 = csr[p], e1 = csr[p + 1];
      unsigned x0 = hs[(e0 & 127) * 64 + lane];
      unsigned x1 = hs[(e1 & 127) * 64 + lane];
      float l0 = bf_lo(x0), h0 = bf_hi(x0);
      float l1 = bf_lo(x1), h1 = bf_hi(x1);
      if (e0 < 0) { ai0 += l0; ai1 += h0; ++nin; } else { ao0 += l0; ao1 += h0; }
      if (e1 < 0) { ai0 += l1; ai1 += h1; ++nin; } else { ao0 += l1; ao1 += h1; }
    }
    if (p < o1) {
      int e0 = csr[p];
      unsigned x0 = hs[(e0 & 127) * 64 + lane];
      float l0 = bf_lo(x0), h0 = bf_hi(x0);
      if (e0 < 0) { ai0 += l0; ai1 += h0; ++nin; } else { ao0 += l0; ao1 += h0; }
    }
    const int dg = o1 - o0;
    const float inv = 1.0f / (float)(dg > 0 ? dg : 1);
    Ain[(size_t)t * 64 + lane] = bfpack(ai0 * inv, ai1 * inv);
    Aout[(size_t)t * 64 + lane] = bfpack(ao0 * inv, ao1 * inv);
    if (lane == 0) { fin[t] = (float)nin * inv; fout[t] = (float)(dg - nin) * inv; }
  }
}

// ---------------- fused MFMA GEMM (K=384) + bias + LN + ReLU, bf16 in/out ----------------
// grid 256, 256 threads (4 waves). Block tile: 128 rows x 128 cols. Wave: 32 rows.
// A-frags direct from global; B (weights) staged per K-step in LDS (80B row stride).
__global__ __launch_bounds__(256) void gemm_kernel(
    const unsigned short* __restrict__ Ain, const unsigned short* __restrict__ Aout,
    const unsigned short* __restrict__ h,
    const unsigned short* __restrict__ Wn, const unsigned short* __restrict__ Wo,
    const unsigned short* __restrict__ Wr,
    const float* __restrict__ bn, const float* __restrict__ bo,
    const float* __restrict__ fin, const float* __restrict__ fout,
    const float* __restrict__ lng, const float* __restrict__ lnb,
    unsigned short* __restrict__ hout) {
  __shared__ unsigned short bs[128 * 40];  // 128 rows x 80B (64B data + 16B pad) = 10 KB
  const int tid = threadIdx.x;
  const int wave = tid >> 6, lane = tid & 63;
  const int q = lane >> 4, m = lane & 15;
  const int rowbase = blockIdx.x * 128 + wave * 32;
  f32x4 acc[2][8];
#pragma unroll
  for (int a = 0; a < 2; ++a)
#pragma unroll
    for (int c = 0; c < 8; ++c) acc[a][c] = (f32x4){0.f, 0.f, 0.f, 0.f};

  const unsigned short* Asegs[3] = {Ain, Aout, h};
  const unsigned short* Wsegs[3] = {Wn, Wo, Wr};
  const size_t r0 = (size_t)(rowbase + m) * HD;
  const size_t r1 = (size_t)(rowbase + 16 + m) * HD;

  for (int step = 0; step < 12; ++step) {
    const int seg = step >> 2;
    const int kl = (step & 3) * 32;
    const unsigned short* W = Wsegs[seg];
    __syncthreads();  // previous step's bs readers done
#pragma unroll
    for (int i = 0; i < 2; ++i) {  // stage 128x32 bf16 weight chunk
      int f = tid + i * 256;
      int n = f >> 2, ch = f & 3;
      *(uint4*)(bs + n * 40 + ch * 8) = *(const uint4*)(W + (size_t)n * HD + kl + ch * 8);
    }
    __syncthreads();
    const unsigned short* As = Asegs[seg];
    short8 a0 = *(const short8*)(As + r0 + kl + q * 8);
    short8 a1 = *(const short8*)(As + r1 + kl + q * 8);
#pragma unroll
    for (int ct = 0; ct < 8; ++ct) {
      short8 bfrag = *(const short8*)(bs + (ct * 16 + m) * 40 + q * 8);
      acc[0][ct] = __builtin_amdgcn_mfma_f32_16x16x32_bf16(a0, bfrag, acc[0][ct], 0, 0, 0);
      acc[1][ct] = __builtin_amdgcn_mfma_f32_16x16x32_bf16(a1, bfrag, acc[1][ct], 0, 0, 0);
    }
  }

  // epilogue: v = acc + fin*bn + fout*bo; LN over 128 cols; ReLU; bf16 store.
  float bnv[8], bov[8], gv[8], bv[8];
#pragma unroll
  for (int ct = 0; ct < 8; ++ct) {
    int c = ct * 16 + m;
    bnv[ct] = bn[c]; bov[ct] = bo[c]; gv[ct] = lng[c]; bv[ct] = lnb[c];
  }
#pragma unroll
  for (int rt = 0; rt < 2; ++rt) {
#pragma unroll
    for (int r = 0; r < 4; ++r) {
      const int R = rowbase + rt * 16 + q * 4 + r;
      const float fi = fin[R], fo = fout[R];
      float v[8];
      float s = 0.f;
#pragma unroll
      for (int ct = 0; ct < 8; ++ct) {
        v[ct] = acc[rt][ct][r] + fi * bnv[ct] + fo * bov[ct];
        s += v[ct];
      }
      s += __shfl_xor(s, 1); s += __shfl_xor(s, 2); s += __shfl_xor(s, 4); s += __shfl_xor(s, 8);
      const float mu = s * (1.0f / 128.0f);
      float sq = 0.f;
#pragma unroll
      for (int ct = 0; ct < 8; ++ct) { float d = v[ct] - mu; sq += d * d; }
      sq += __shfl_xor(sq, 1); sq += __shfl_xor(sq, 2); sq += __shfl_xor(sq, 4); sq += __shfl_xor(sq, 8);
      const float rstd = rsqrtf(sq * (1.0f / 128.0f) + 1e-5f);
#pragma unroll
      for (int ct = 0; ct < 8; ++ct) {
        float o = fmaxf((v[ct] - mu) * rstd * gv[ct] + bv[ct], 0.0f);
        hout[(size_t)R * HD + ct * 16 + m] = f2bf(o);
      }
    }
  }
}

// ---------------- pooled[g,c,h] = sum_n s[g,n,c]*h[g,n,h] (h is bf16) ----------------
__global__ __launch_bounds__(256) void pool_kernel(const unsigned short* __restrict__ h, const float* __restrict__ s,
                                                   float* __restrict__ pooled, float* __restrict__ colsum) {
  __shared__ float xs[128][128];  // 64 KB
  __shared__ float ss[128][16];   // 8 KB
  const int g = blockIdx.x;
  const int tid = threadIdx.x;
  const unsigned short* hg = h + (size_t)g * NPGd * HD;
  const float* sg = s + (size_t)g * NPGd * CCd;
#pragma unroll
  for (int i = 0; i < 8; ++i) {   // 2048 x 16B bf16 loads
    int f = tid + i * 256;
    int n = f >> 4, ch = f & 15;
    uint4 v = *(const uint4*)(hg + (size_t)n * HD + ch * 8);
    float* dst = &xs[n][ch * 8];
    dst[0] = bf_lo(v.x); dst[1] = bf_hi(v.x);
    dst[2] = bf_lo(v.y); dst[3] = bf_hi(v.y);
    dst[4] = bf_lo(v.z); dst[5] = bf_hi(v.z);
    dst[6] = bf_lo(v.w); dst[7] = bf_hi(v.w);
  }
#pragma unroll
  for (int i = 0; i < 2; ++i) {
    int f = tid + i * 256;
    int n = f >> 2;
    int qd = (f & 3) << 2;
    *(float4*)&ss[n][qd] = *(const float4*)(sg + n * CCd + qd);
  }
  __syncthreads();
  const int c = tid >> 4;
  const int j0 = (tid & 15) << 3;
  float acc[8] = {0, 0, 0, 0, 0, 0, 0, 0};
  for (int n = 0; n < 128; ++n) {
    float sv = ss[n][c];
    float4 x0 = *(const float4*)&xs[n][j0];
    float4 x1 = *(const float4*)&xs[n][j0 + 4];
    acc[0] += sv * x0.x; acc[1] += sv * x0.y; acc[2] += sv * x0.z; acc[3] += sv * x0.w;
    acc[4] += sv * x1.x; acc[5] += sv * x1.y; acc[6] += sv * x1.z; acc[7] += sv * x1.w;
  }
  float* pg = pooled + ((size_t)g * CCd + c) * HD + j0;
  *(float4*)pg = make_float4(acc[0], acc[1], acc[2], acc[3]);
  *(float4*)(pg + 4) = make_float4(acc[4], acc[5], acc[6], acc[7]);
  if (tid < CCd) {
    float cs = 0.f;
    for (int n = 0; n < 128; ++n) cs += ss[n][tid];
    colsum[g * CCd + tid] = cs;
  }
}

// ---------------- final LN + lin + mask + per-graph sums ----------------
__global__ __launch_bounds__(256) void final_kernel(const float* __restrict__ pooled, const float* __restrict__ colsum,
                                                    const float* __restrict__ flng, const float* __restrict__ flnb,
                                                    const float* __restrict__ linw, const float* __restrict__ bias,
                                                    float* __restrict__ out, float* __restrict__ l1g) {
  const int g = blockIdx.x;
  const int tid = threadIdx.x;
  const int c = tid >> 4;
  const int j0 = (tid & 15) << 3;
  const float* row = pooled + ((size_t)g * CCd + c) * HD + j0;
  float4 rr0 = *(const float4*)row;
  float4 rr1 = *(const float4*)(row + 4);
  float v[8] = {rr0.x, rr0.y, rr0.z, rr0.w, rr1.x, rr1.y, rr1.z, rr1.w};
  float sum = 0.f;
#pragma unroll
  for (int jj = 0; jj < 8; ++jj) sum += v[jj];
#pragma unroll
  for (int mk = 1; mk < 16; mk <<= 1) sum += __shfl_xor(sum, mk, 64);
  float mu = sum * (1.0f / 128.0f);
  float sq = 0.f;
#pragma unroll
  for (int jj = 0; jj < 8; ++jj) { float d = v[jj] - mu; sq += d * d; }
#pragma unroll
  for (int mk = 1; mk < 16; mk <<= 1) sq += __shfl_xor(sq, mk, 64);
  float rstd = rsqrtf(sq * (1.0f / 128.0f) + 1e-5f);
  float dot = 0.f;
#pragma unroll
  for (int jj = 0; jj < 8; ++jj) {
    float nv = (v[jj] - mu) * rstd * flng[j0 + jj] + flnb[j0 + jj];
    dot += nv * linw[j0 + jj];
  }
#pragma unroll
  for (int mk = 1; mk < 16; mk <<= 1) dot += __shfl_xor(dot, mk, 64);
  __shared__ float xcs[CCd], axcs[CCd], ms[CCd];
  if ((tid & 15) == 0) {
    float cm = (colsum[g * CCd + c] > 0.f) ? 1.0f : 0.0f;
    float xcv = dot * cm;
    out[257 + g * CCd + c] = xcv;  // xc block after out(256) + losses(1)
    xcs[c] = xcv; axcs[c] = fabsf(xcv); ms[c] = cm;
  }
  __syncthreads();
  if (tid == 0) {
    float so = 0.f, sa = 0.f, sd = 0.f;
#pragma unroll
    for (int k = 0; k < CCd; ++k) { so += xcs[k]; sa += axcs[k]; sd += ms[k] + 1e-7f; }
    out[g] = so + bias[0];
    l1g[g] = sa / sd;
  }
}

// ---------------- losses (fp32-exact on Wo/bo) ----------------
__global__ __launch_bounds__(256) void loss_kernel(const float* __restrict__ Wo, const float* __restrict__ bo,
                                                   const float* __restrict__ l1g, float* __restrict__ outp) {
  const int tid = threadIdx.x;
  float s = 0.f;
  for (int i = tid; i < LLd * HD * HD; i += 256) s += fabsf(Wo[i]);
  for (int i = tid; i < LLd * HD; i += 256) s += fabsf(bo[i]);
  float s2 = (tid < GG) ? l1g[tid] : 0.f;
#pragma unroll
  for (int mk = 1; mk < 64; mk <<= 1) { s += __shfl_xor(s, mk, 64); s2 += __shfl_xor(s2, mk, 64); }
  __shared__ float rs[4], rs2[4];
  int w = tid >> 6;
  if ((tid & 63) == 0) { rs[w] = s; rs2[w] = s2; }
  __syncthreads();
  if (tid == 0) {
    float reg = rs[0] + rs[1] + rs[2] + rs[3];
    float l1 = (rs2[0] + rs2[1] + rs2[2] + rs2[3]) * (1.0f / GG);
    outp[0] = 0.01f * reg + 0.01f * l1;
  }
}

extern "C" void kernel_launch(void* const* d_in, const int* in_sizes, int n_in,
                              void* d_out, int out_size, void* d_ws, size_t ws_size,
                              hipStream_t stream) {
  (void)in_sizes; (void)n_in; (void)out_size; (void)ws_size;
  const float* x    = (const float*)d_in[0];
  const int*   ei   = (const int*)d_in[1];
  const int*   mask = (const int*)d_in[2];
  const float* s    = (const float*)d_in[3];
  const float* Wn   = (const float*)d_in[5];
  const float* bn   = (const float*)d_in[6];
  const float* Wo   = (const float*)d_in[7];
  const float* bo   = (const float*)d_in[8];
  const float* Wr   = (const float*)d_in[9];
  const float* lng  = (const float*)d_in[10];
  const float* lnb  = (const float*)d_in[11];
  const float* flng = (const float*)d_in[12];
  const float* flnb = (const float*)d_in[13];
  const float* linw = (const float*)d_in[14];
  const float* bias = (const float*)d_in[15];
  float* out = (float*)d_out;

  char* ws = (char*)d_ws;
  size_t off = 0;
  auto alloc = [&](size_t b) { char* p = ws + off; off += (b + 255) & ~(size_t)255; return p; };
  int* deg      = (int*)alloc((size_t)NN * 4);
  int* offs     = (int*)alloc((size_t)(NN + 1) * 4);
  int* fill     = (int*)alloc((size_t)NN * 4);
  int* csr      = (int*)alloc((size_t)EE * 4);
  unsigned short* xb  = (unsigned short*)alloc((size_t)NN * HD * 2);
  unsigned short* hA  = (unsigned short*)alloc((size_t)NN * HD * 2);
  unsigned short* hB  = (unsigned short*)alloc((size_t)NN * HD * 2);
  unsigned short* Ain = (unsigned short*)alloc((size_t)NN * HD * 2);
  unsigned short* Aout= (unsigned short*)alloc((size_t)NN * HD * 2);
  float* fin    = (float*)alloc((size_t)NN * 4);
  float* fout   = (float*)alloc((size_t)NN * 4);
  unsigned short* Wnb = (unsigned short*)alloc((size_t)LLd * HD * HD * 2);
  unsigned short* Wob = (unsigned short*)alloc((size_t)LLd * HD * HD * 2);
  unsigned short* Wrb = (unsigned short*)alloc((size_t)LLd * HD * HD * 2);
  float* pooled = (float*)alloc((size_t)GG * CCd * HD * 4);
  float* colsum = (float*)alloc((size_t)GG * CCd * 4);
  float* l1g    = (float*)alloc((size_t)GG * 4);

  const int* srcA = ei;
  const int* tgtA = ei + EE;

  hipMemsetAsync(deg, 0, (size_t)NN * 4, stream);
  hipMemsetAsync(fill, 0, (size_t)NN * 4, stream);
  convert_x_kernel<<<NN * HD / (256 * 8), 256, 0, stream>>>(x, (unsigned*)xb);
  convert_w_kernel<<<LLd * HD * HD / (256 * 4), 256, 0, stream>>>(Wn, Wo, Wr, (unsigned*)Wnb, (unsigned*)Wob, (unsigned*)Wrb);
  count_kernel<<<EE / 256, 256, 0, stream>>>(tgtA, deg);
  scan_kernel<<<1, 1024, 0, stream>>>(deg, offs);
  scatter_kernel<<<EE / 256, 256, 0, stream>>>(srcA, tgtA, mask, offs, fill, csr);

  const unsigned short* hcur = xb;
  unsigned short* houts[3] = {hA, hB, hA};
  for (int i = 0; i < LLd; ++i) {
    agg_kernel<<<GG * 4, 256, 0, stream>>>((const unsigned*)hcur, offs, csr,
                                           (unsigned*)Ain, (unsigned*)Aout, fin, fout);
    gemm_kernel<<<NN / 128, 256, 0, stream>>>(Ain, Aout, hcur,
        Wnb + (size_t)i * HD * HD, Wob + (size_t)i * HD * HD, Wrb + (size_t)i * HD * HD,
        bn + (size_t)i * HD, bo + (size_t)i * HD, fin, fout,
        lng + (size_t)i * HD, lnb + (size_t)i * HD, houts[i]);
    hcur = houts[i];
  }
  pool_kernel<<<GG, 256, 0, stream>>>(hcur, s, pooled, colsum);
  final_kernel<<<GG, 256, 0, stream>>>(pooled, colsum, flng, flnb, linw, bias, out, l1g);
  loss_kernel<<<1, 256, 0, stream>>>(Wo, bo, l1g, out + 256);
}

// Round 3
// 255.447 us; speedup vs baseline: 2.0814x; 1.3629x over previous
//
#include <hip/hip_runtime.h>

#define NN   32768
#define HD   128
#define EE   524288
#define GG   256
#define EPG  2048
#define NPGd 128
#define CCd  16
#define LLd  3

typedef short short8 __attribute__((ext_vector_type(8)));   // 8 bf16 = 4 VGPRs
typedef float f32x4 __attribute__((ext_vector_type(4)));

__device__ __forceinline__ unsigned short f2bf(float f) {
  unsigned u = __builtin_bit_cast(unsigned, f);
  return (unsigned short)((u + 0x7FFFu + ((u >> 16) & 1u)) >> 16);  // RNE
}
__device__ __forceinline__ float bf_lo(unsigned p) { return __builtin_bit_cast(float, p << 16); }
__device__ __forceinline__ float bf_hi(unsigned p) { return __builtin_bit_cast(float, p & 0xFFFF0000u); }
__device__ __forceinline__ unsigned bfpack(float a, float b) {
  return (unsigned)f2bf(a) | ((unsigned)f2bf(b) << 16);
}

// ---------------- converts ----------------
__global__ __launch_bounds__(256) void convert_x_kernel(const float* __restrict__ x, unsigned* __restrict__ xb) {
  int i = blockIdx.x * 256 + threadIdx.x;   // handles 8 floats -> 4 uints
  const float4* src = (const float4*)(x + (size_t)i * 8);
  float4 a = src[0], b = src[1];
  uint4 o;
  o.x = bfpack(a.x, a.y); o.y = bfpack(a.z, a.w);
  o.z = bfpack(b.x, b.y); o.w = bfpack(b.z, b.w);
  *(uint4*)(xb + (size_t)i * 4) = o;
}

// convert weights to bf16 AND accumulate reg_loss = sum|Wo| + sum|bo| into wsreg (atomic)
__global__ __launch_bounds__(256) void convert_w_kernel(const float* __restrict__ Wn, const float* __restrict__ Wo,
                                                        const float* __restrict__ Wr, const float* __restrict__ bo,
                                                        unsigned* __restrict__ Wnb, unsigned* __restrict__ Wob,
                                                        unsigned* __restrict__ Wrb, float* __restrict__ wsreg) {
  int i = blockIdx.x * 256 + threadIdx.x;   // 48 blocks; 4 floats per array per thread
  float4 a = *(const float4*)(Wn + (size_t)i * 4);
  float4 b = *(const float4*)(Wo + (size_t)i * 4);
  float4 c = *(const float4*)(Wr + (size_t)i * 4);
  *(uint2*)(Wnb + (size_t)i * 2) = make_uint2(bfpack(a.x, a.y), bfpack(a.z, a.w));
  *(uint2*)(Wob + (size_t)i * 2) = make_uint2(bfpack(b.x, b.y), bfpack(b.z, b.w));
  *(uint2*)(Wrb + (size_t)i * 2) = make_uint2(bfpack(c.x, c.y), bfpack(c.z, c.w));
  float s = fabsf(b.x) + fabsf(b.y) + fabsf(b.z) + fabsf(b.w);
  if (blockIdx.x == 0 && threadIdx.x < 96) {       // 384 bo elements
    float4 d = *(const float4*)(bo + threadIdx.x * 4);
    s += fabsf(d.x) + fabsf(d.y) + fabsf(d.z) + fabsf(d.w);
  }
#pragma unroll
  for (int mk = 1; mk < 64; mk <<= 1) s += __shfl_xor(s, mk, 64);
  if ((threadIdx.x & 63) == 0) atomicAdd(wsreg, s);
}

// ---------------- per-graph CSR build (edges are contiguous per graph: 2048 each) ----------------
__global__ __launch_bounds__(256) void build_csr_kernel(const int* __restrict__ src, const int* __restrict__ tgt,
                                                        const int* __restrict__ mask,
                                                        int* __restrict__ offs, int* __restrict__ csr) {
  __shared__ int cnt[128];
  __shared__ int base[128];
  const int g = blockIdx.x;
  const int tid = threadIdx.x;
  const int e0 = g * EPG;
  if (tid < 128) cnt[tid] = 0;
  __syncthreads();
  int tl[8], sl[8];
#pragma unroll
  for (int i = 0; i < 8; ++i) {
    int e = e0 + i * 256 + tid;
    tl[i] = tgt[e] & 127;
    int enc = src[e] & 127;
    if (mask[e] != 0) enc |= (int)0x80000000;
    sl[i] = enc;
    atomicAdd(&cnt[tl[i]], 1);
  }
  __syncthreads();
  if (tid < 64) {   // wave 0: scan 128 counts (2 per lane)
    int a = cnt[tid * 2], b = cnt[tid * 2 + 1];
    int s = a + b;
#pragma unroll
    for (int d = 1; d < 64; d <<= 1) {
      int t = __shfl_up(s, d);
      if (tid >= d) s += t;
    }
    base[tid * 2] = s - a - b;
    base[tid * 2 + 1] = s - b;
    offs[g * 128 + tid * 2] = e0 + s - a - b;
    offs[g * 128 + tid * 2 + 1] = e0 + s - b;
    cnt[tid * 2] = 0;
    cnt[tid * 2 + 1] = 0;
  }
  __syncthreads();
#pragma unroll
  for (int i = 0; i < 8; ++i) {
    int p = atomicAdd(&cnt[tl[i]], 1);
    csr[e0 + base[tl[i]] + p] = sl[i];
  }
  if (g == 0 && tid == 0) offs[NN] = EE;
}

// ---------------- agg: one block per graph, 16 waves; stage h once; shfl-broadcast CSR ----------------
__global__ __launch_bounds__(1024) void agg_kernel(const unsigned* __restrict__ h,  // bf16x2 [NN][64]
                                                   const int* __restrict__ offs, const int* __restrict__ csr,
                                                   unsigned* __restrict__ Ain, unsigned* __restrict__ Aout,
                                                   float* __restrict__ fin, float* __restrict__ fout) {
  __shared__ unsigned hs[128 * 64];  // 32 KB
  const int g = blockIdx.x;
  const int tid = threadIdx.x;
  const int wave = tid >> 6, lane = tid & 63;
  const uint4* hg4 = (const uint4*)(h + (size_t)g * 128 * 64);
  uint4* hs4 = (uint4*)hs;
  hs4[tid] = hg4[tid];
  hs4[tid + 1024] = hg4[tid + 1024];
  __syncthreads();
#pragma unroll 1
  for (int rep = 0; rep < 8; ++rep) {
    const int t = g * 128 + wave * 8 + rep;
    const int o0 = offs[t], o1 = offs[t + 1];
    const int dg = o1 - o0;
    int my = (o0 + lane < o1) ? csr[o0 + lane] : 0;   // coalesced prefetch of this node's edges
    float ai0 = 0.f, ai1 = 0.f, ao0 = 0.f, ao1 = 0.f;
    int nin = 0;
    const int nq = dg < 64 ? dg : 64;
    for (int j = 0; j < nq; ++j) {
      int enc = __shfl(my, j);
      unsigned xv = hs[(enc & 127) * 64 + lane];
      float lo = bf_lo(xv), hi = bf_hi(xv);
      if (enc < 0) { ai0 += lo; ai1 += hi; ++nin; } else { ao0 += lo; ao1 += hi; }
    }
    for (int p = o0 + 64; p < o1; ++p) {              // astronomically rare tail (deg>64)
      int enc = csr[p];
      unsigned xv = hs[(enc & 127) * 64 + lane];
      float lo = bf_lo(xv), hi = bf_hi(xv);
      if (enc < 0) { ai0 += lo; ai1 += hi; ++nin; } else { ao0 += lo; ao1 += hi; }
    }
    const float inv = 1.0f / (float)(dg > 0 ? dg : 1);
    Ain[(size_t)t * 64 + lane] = bfpack(ai0 * inv, ai1 * inv);
    Aout[(size_t)t * 64 + lane] = bfpack(ao0 * inv, ao1 * inv);
    if (lane == 0) { fin[t] = (float)nin * inv; fout[t] = (float)(dg - nin) * inv; }
  }
}

// ---------------- fused MFMA GEMM (K=384) + bias + LN + ReLU, bf16 in/out ----------------
__global__ __launch_bounds__(256) void gemm_kernel(
    const unsigned short* __restrict__ Ain, const unsigned short* __restrict__ Aout,
    const unsigned short* __restrict__ h,
    const unsigned short* __restrict__ Wn, const unsigned short* __restrict__ Wo,
    const unsigned short* __restrict__ Wr,
    const float* __restrict__ bn, const float* __restrict__ bo,
    const float* __restrict__ fin, const float* __restrict__ fout,
    const float* __restrict__ lng, const float* __restrict__ lnb,
    unsigned short* __restrict__ hout) {
  __shared__ unsigned short bs[128 * 40];  // 128 rows x 80B (64B data + 16B pad) = 10 KB
  const int tid = threadIdx.x;
  const int wave = tid >> 6, lane = tid & 63;
  const int q = lane >> 4, m = lane & 15;
  const int rowbase = blockIdx.x * 128 + wave * 32;
  f32x4 acc[2][8];
#pragma unroll
  for (int a = 0; a < 2; ++a)
#pragma unroll
    for (int c = 0; c < 8; ++c) acc[a][c] = (f32x4){0.f, 0.f, 0.f, 0.f};

  const unsigned short* Asegs[3] = {Ain, Aout, h};
  const unsigned short* Wsegs[3] = {Wn, Wo, Wr};
  const size_t r0 = (size_t)(rowbase + m) * HD;
  const size_t r1 = (size_t)(rowbase + 16 + m) * HD;

  for (int step = 0; step < 12; ++step) {
    const int seg = step >> 2;
    const int kl = (step & 3) * 32;
    const unsigned short* W = Wsegs[seg];
    __syncthreads();
#pragma unroll
    for (int i = 0; i < 2; ++i) {  // stage 128x32 bf16 weight chunk
      int f = tid + i * 256;
      int n = f >> 2, ch = f & 3;
      *(uint4*)(bs + n * 40 + ch * 8) = *(const uint4*)(W + (size_t)n * HD + kl + ch * 8);
    }
    __syncthreads();
    const unsigned short* As = Asegs[seg];
    short8 a0 = *(const short8*)(As + r0 + kl + q * 8);
    short8 a1 = *(const short8*)(As + r1 + kl + q * 8);
#pragma unroll
    for (int ct = 0; ct < 8; ++ct) {
      short8 bfrag = *(const short8*)(bs + (ct * 16 + m) * 40 + q * 8);
      acc[0][ct] = __builtin_amdgcn_mfma_f32_16x16x32_bf16(a0, bfrag, acc[0][ct], 0, 0, 0);
      acc[1][ct] = __builtin_amdgcn_mfma_f32_16x16x32_bf16(a1, bfrag, acc[1][ct], 0, 0, 0);
    }
  }

  float bnv[8], bov[8], gv[8], bv[8];
#pragma unroll
  for (int ct = 0; ct < 8; ++ct) {
    int c = ct * 16 + m;
    bnv[ct] = bn[c]; bov[ct] = bo[c]; gv[ct] = lng[c]; bv[ct] = lnb[c];
  }
#pragma unroll
  for (int rt = 0; rt < 2; ++rt) {
#pragma unroll
    for (int r = 0; r < 4; ++r) {
      const int R = rowbase + rt * 16 + q * 4 + r;
      const float fi = fin[R], fo = fout[R];
      float v[8];
      float s = 0.f;
#pragma unroll
      for (int ct = 0; ct < 8; ++ct) {
        v[ct] = acc[rt][ct][r] + fi * bnv[ct] + fo * bov[ct];
        s += v[ct];
      }
      s += __shfl_xor(s, 1); s += __shfl_xor(s, 2); s += __shfl_xor(s, 4); s += __shfl_xor(s, 8);
      const float mu = s * (1.0f / 128.0f);
      float sq = 0.f;
#pragma unroll
      for (int ct = 0; ct < 8; ++ct) { float d = v[ct] - mu; sq += d * d; }
      sq += __shfl_xor(sq, 1); sq += __shfl_xor(sq, 2); sq += __shfl_xor(sq, 4); sq += __shfl_xor(sq, 8);
      const float rstd = rsqrtf(sq * (1.0f / 128.0f) + 1e-5f);
#pragma unroll
      for (int ct = 0; ct < 8; ++ct) {
        float o = fmaxf((v[ct] - mu) * rstd * gv[ct] + bv[ct], 0.0f);
        hout[(size_t)R * HD + ct * 16 + m] = f2bf(o);
      }
    }
  }
}

// ---------------- pooled[g,c,h] = sum_n s[g,n,c]*h[g,n,h] (h is bf16) ----------------
__global__ __launch_bounds__(256) void pool_kernel(const unsigned short* __restrict__ h, const float* __restrict__ s,
                                                   float* __restrict__ pooled, float* __restrict__ colsum) {
  __shared__ float xs[128][128];  // 64 KB
  __shared__ float ss[128][16];   // 8 KB
  const int g = blockIdx.x;
  const int tid = threadIdx.x;
  const unsigned short* hg = h + (size_t)g * NPGd * HD;
  const float* sg = s + (size_t)g * NPGd * CCd;
#pragma unroll
  for (int i = 0; i < 8; ++i) {
    int f = tid + i * 256;
    int n = f >> 4, ch = f & 15;
    uint4 v = *(const uint4*)(hg + (size_t)n * HD + ch * 8);
    float* dst = &xs[n][ch * 8];
    dst[0] = bf_lo(v.x); dst[1] = bf_hi(v.x);
    dst[2] = bf_lo(v.y); dst[3] = bf_hi(v.y);
    dst[4] = bf_lo(v.z); dst[5] = bf_hi(v.z);
    dst[6] = bf_lo(v.w); dst[7] = bf_hi(v.w);
  }
#pragma unroll
  for (int i = 0; i < 2; ++i) {
    int f = tid + i * 256;
    int n = f >> 2;
    int qd = (f & 3) << 2;
    *(float4*)&ss[n][qd] = *(const float4*)(sg + n * CCd + qd);
  }
  __syncthreads();
  const int c = tid >> 4;
  const int j0 = (tid & 15) << 3;
  float acc[8] = {0, 0, 0, 0, 0, 0, 0, 0};
  for (int n = 0; n < 128; ++n) {
    float sv = ss[n][c];
    float4 x0 = *(const float4*)&xs[n][j0];
    float4 x1 = *(const float4*)&xs[n][j0 + 4];
    acc[0] += sv * x0.x; acc[1] += sv * x0.y; acc[2] += sv * x0.z; acc[3] += sv * x0.w;
    acc[4] += sv * x1.x; acc[5] += sv * x1.y; acc[6] += sv * x1.z; acc[7] += sv * x1.w;
  }
  float* pg = pooled + ((size_t)g * CCd + c) * HD + j0;
  *(float4*)pg = make_float4(acc[0], acc[1], acc[2], acc[3]);
  *(float4*)(pg + 4) = make_float4(acc[4], acc[5], acc[6], acc[7]);
  if (tid < CCd) {
    float cs = 0.f;
    for (int n = 0; n < 128; ++n) cs += ss[n][tid];
    colsum[g * CCd + tid] = cs;
  }
}

// ---------------- final LN + lin + mask + per-graph sums ----------------
__global__ __launch_bounds__(256) void final_kernel(const float* __restrict__ pooled, const float* __restrict__ colsum,
                                                    const float* __restrict__ flng, const float* __restrict__ flnb,
                                                    const float* __restrict__ linw, const float* __restrict__ bias,
                                                    float* __restrict__ out, float* __restrict__ l1g) {
  const int g = blockIdx.x;
  const int tid = threadIdx.x;
  const int c = tid >> 4;
  const int j0 = (tid & 15) << 3;
  const float* row = pooled + ((size_t)g * CCd + c) * HD + j0;
  float4 rr0 = *(const float4*)row;
  float4 rr1 = *(const float4*)(row + 4);
  float v[8] = {rr0.x, rr0.y, rr0.z, rr0.w, rr1.x, rr1.y, rr1.z, rr1.w};
  float sum = 0.f;
#pragma unroll
  for (int jj = 0; jj < 8; ++jj) sum += v[jj];
#pragma unroll
  for (int mk = 1; mk < 16; mk <<= 1) sum += __shfl_xor(sum, mk, 64);
  float mu = sum * (1.0f / 128.0f);
  float sq = 0.f;
#pragma unroll
  for (int jj = 0; jj < 8; ++jj) { float d = v[jj] - mu; sq += d * d; }
#pragma unroll
  for (int mk = 1; mk < 16; mk <<= 1) sq += __shfl_xor(sq, mk, 64);
  float rstd = rsqrtf(sq * (1.0f / 128.0f) + 1e-5f);
  float dot = 0.f;
#pragma unroll
  for (int jj = 0; jj < 8; ++jj) {
    float nv = (v[jj] - mu) * rstd * flng[j0 + jj] + flnb[j0 + jj];
    dot += nv * linw[j0 + jj];
  }
#pragma unroll
  for (int mk = 1; mk < 16; mk <<= 1) dot += __shfl_xor(dot, mk, 64);
  __shared__ float xcs[CCd], axcs[CCd], ms[CCd];
  if ((tid & 15) == 0) {
    float cm = (colsum[g * CCd + c] > 0.f) ? 1.0f : 0.0f;
    float xcv = dot * cm;
    out[257 + g * CCd + c] = xcv;  // xc block after out(256) + losses(1)
    xcs[c] = xcv; axcs[c] = fabsf(xcv); ms[c] = cm;
  }
  __syncthreads();
  if (tid == 0) {
    float so = 0.f, sa = 0.f, sd = 0.f;
#pragma unroll
    for (int k = 0; k < CCd; ++k) { so += xcs[k]; sa += axcs[k]; sd += ms[k] + 1e-7f; }
    out[g] = so + bias[0];
    l1g[g] = sa / sd;
  }
}

// ---------------- combine: losses = 0.01*reg + 0.01*mean_g(l1g) ----------------
__global__ __launch_bounds__(256) void combine_kernel(const float* __restrict__ l1g, const float* __restrict__ wsreg,
                                                      float* __restrict__ outp) {
  const int tid = threadIdx.x;
  float s2 = l1g[tid];
#pragma unroll
  for (int mk = 1; mk < 64; mk <<= 1) s2 += __shfl_xor(s2, mk, 64);
  __shared__ float rs2[4];
  if ((tid & 63) == 0) rs2[tid >> 6] = s2;
  __syncthreads();
  if (tid == 0) {
    float l1 = (rs2[0] + rs2[1] + rs2[2] + rs2[3]) * (1.0f / GG);
    outp[0] = 0.01f * wsreg[0] + 0.01f * l1;
  }
}

extern "C" void kernel_launch(void* const* d_in, const int* in_sizes, int n_in,
                              void* d_out, int out_size, void* d_ws, size_t ws_size,
                              hipStream_t stream) {
  (void)in_sizes; (void)n_in; (void)out_size; (void)ws_size;
  const float* x    = (const float*)d_in[0];
  const int*   ei   = (const int*)d_in[1];
  const int*   mask = (const int*)d_in[2];
  const float* s    = (const float*)d_in[3];
  const float* Wn   = (const float*)d_in[5];
  const float* bn   = (const float*)d_in[6];
  const float* Wo   = (const float*)d_in[7];
  const float* bo   = (const float*)d_in[8];
  const float* Wr   = (const float*)d_in[9];
  const float* lng  = (const float*)d_in[10];
  const float* lnb  = (const float*)d_in[11];
  const float* flng = (const float*)d_in[12];
  const float* flnb = (const float*)d_in[13];
  const float* linw = (const float*)d_in[14];
  const float* bias = (const float*)d_in[15];
  float* out = (float*)d_out;

  char* ws = (char*)d_ws;
  size_t off = 0;
  auto alloc = [&](size_t b) { char* p = ws + off; off += (b + 255) & ~(size_t)255; return p; };
  int* offs     = (int*)alloc((size_t)(NN + 1) * 4);
  int* csr      = (int*)alloc((size_t)EE * 4);
  unsigned short* xb  = (unsigned short*)alloc((size_t)NN * HD * 2);
  unsigned short* hA  = (unsigned short*)alloc((size_t)NN * HD * 2);
  unsigned short* hB  = (unsigned short*)alloc((size_t)NN * HD * 2);
  unsigned short* Ain = (unsigned short*)alloc((size_t)NN * HD * 2);
  unsigned short* Aout= (unsigned short*)alloc((size_t)NN * HD * 2);
  float* fin    = (float*)alloc((size_t)NN * 4);
  float* fout   = (float*)alloc((size_t)NN * 4);
  unsigned short* Wnb = (unsigned short*)alloc((size_t)LLd * HD * HD * 2);
  unsigned short* Wob = (unsigned short*)alloc((size_t)LLd * HD * HD * 2);
  unsigned short* Wrb = (unsigned short*)alloc((size_t)LLd * HD * HD * 2);
  float* pooled = (float*)alloc((size_t)GG * CCd * HD * 4);
  float* colsum = (float*)alloc((size_t)GG * CCd * 4);
  float* l1g    = (float*)alloc((size_t)GG * 4);
  float* wsreg  = (float*)alloc(256);

  const int* srcA = ei;
  const int* tgtA = ei + EE;

  hipMemsetAsync(wsreg, 0, 4, stream);
  convert_x_kernel<<<NN * HD / (256 * 8), 256, 0, stream>>>(x, (unsigned*)xb);
  convert_w_kernel<<<LLd * HD * HD / (256 * 4), 256, 0, stream>>>(Wn, Wo, Wr, bo,
      (unsigned*)Wnb, (unsigned*)Wob, (unsigned*)Wrb, wsreg);
  build_csr_kernel<<<GG, 256, 0, stream>>>(srcA, tgtA, mask, offs, csr);

  const unsigned short* hcur = xb;
  unsigned short* houts[3] = {hA, hB, hA};
  for (int i = 0; i < LLd; ++i) {
    agg_kernel<<<GG, 1024, 0, stream>>>((const unsigned*)hcur, offs, csr,
                                        (unsigned*)Ain, (unsigned*)Aout, fin, fout);
    gemm_kernel<<<NN / 128, 256, 0, stream>>>(Ain, Aout, hcur,
        Wnb + (size_t)i * HD * HD, Wob + (size_t)i * HD * HD, Wrb + (size_t)i * HD * HD,
        bn + (size_t)i * HD, bo + (size_t)i * HD, fin, fout,
        lng + (size_t)i * HD, lnb + (size_t)i * HD, houts[i]);
    hcur = houts[i];
  }
  pool_kernel<<<GG, 256, 0, stream>>>(hcur, s, pooled, colsum);
  final_kernel<<<GG, 256, 0, stream>>>(pooled, colsum, flng, flnb, linw, bias, out, l1g);
  combine_kernel<<<1, 256, 0, stream>>>(l1g, wsreg, out + 256);
}

// Round 4
// 160.309 us; speedup vs baseline: 3.3166x; 1.5935x over previous
//
#include <hip/hip_runtime.h>

#define NN   32768
#define HD   128
#define EE   524288
#define GG   256
#define EPG  2048
#define CCd  16
#define LLd  3

typedef short short8 __attribute__((ext_vector_type(8)));   // 8 bf16 = 4 VGPRs
typedef float f32x4 __attribute__((ext_vector_type(4)));

__device__ __forceinline__ unsigned short f2bf(float f) {
  unsigned u = __builtin_bit_cast(unsigned, f);
  return (unsigned short)((u + 0x7FFFu + ((u >> 16) & 1u)) >> 16);  // RNE
}
__device__ __forceinline__ unsigned bfpack(float a, float b) {
  return (unsigned)f2bf(a) | ((unsigned)f2bf(b) << 16);
}

// ---------------- convert weights to bf16 + reg_loss accumulate ----------------
__global__ __launch_bounds__(256) void convert_w_kernel(const float* __restrict__ Wn, const float* __restrict__ Wo,
                                                        const float* __restrict__ Wr, const float* __restrict__ bo,
                                                        unsigned* __restrict__ Wnb, unsigned* __restrict__ Wob,
                                                        unsigned* __restrict__ Wrb, float* __restrict__ wsreg) {
  int i = blockIdx.x * 256 + threadIdx.x;   // 48 blocks; 4 floats per array per thread
  float4 a = *(const float4*)(Wn + (size_t)i * 4);
  float4 b = *(const float4*)(Wo + (size_t)i * 4);
  float4 c = *(const float4*)(Wr + (size_t)i * 4);
  *(uint2*)(Wnb + (size_t)i * 2) = make_uint2(bfpack(a.x, a.y), bfpack(a.z, a.w));
  *(uint2*)(Wob + (size_t)i * 2) = make_uint2(bfpack(b.x, b.y), bfpack(b.z, b.w));
  *(uint2*)(Wrb + (size_t)i * 2) = make_uint2(bfpack(c.x, c.y), bfpack(c.z, c.w));
  float s = fabsf(b.x) + fabsf(b.y) + fabsf(b.z) + fabsf(b.w);
  if (blockIdx.x == 0 && threadIdx.x < 96) {       // 384 bo elements
    float4 d = *(const float4*)(bo + threadIdx.x * 4);
    s += fabsf(d.x) + fabsf(d.y) + fabsf(d.z) + fabsf(d.w);
  }
#pragma unroll
  for (int mk = 1; mk < 64; mk <<= 1) s += __shfl_xor(s, mk, 64);
  if ((threadIdx.x & 63) == 0) atomicAdd(wsreg, s);
}

// ---------------- per-graph dense adjacency (scaled bf16) + fin/fout ----------------
// Mb[g][dir][t][s] bf16 = count(dir,t,s) * inv_cnt(t).  dir0 = mask(in/Wn), dir1 = out/Wo.
__global__ __launch_bounds__(256) void build_m_kernel(const int* __restrict__ src, const int* __restrict__ tgt,
                                                      const int* __restrict__ mask,
                                                      unsigned* __restrict__ Mb, float* __restrict__ fin,
                                                      float* __restrict__ fout) {
  __shared__ unsigned Mi[2 * 128 * 64];   // 64 KB: packed int16 counts [dir][t][s/2]
  const int g = blockIdx.x;
  const int tid = threadIdx.x;
  for (int i = tid; i < 16384; i += 256) Mi[i] = 0;
  __syncthreads();
  const int e0 = g * EPG;
#pragma unroll
  for (int i = 0; i < 8; ++i) {
    int e = e0 + i * 256 + tid;
    int t = tgt[e] & 127;
    int sl = src[e] & 127;
    int dir = (mask[e] != 0) ? 0 : 1;
    atomicAdd(&Mi[dir * 8192 + t * 64 + (sl >> 1)], 1u << ((sl & 1) * 16));
  }
  __syncthreads();
  const int t = tid >> 1, p = tid & 1;
  unsigned nin = 0, nout = 0;
#pragma unroll 4
  for (int k = 0; k < 32; ++k) { unsigned v = Mi[t * 64 + p * 32 + k]; nin += (v & 0xffffu) + (v >> 16); }
#pragma unroll 4
  for (int k = 0; k < 32; ++k) { unsigned v = Mi[8192 + t * 64 + p * 32 + k]; nout += (v & 0xffffu) + (v >> 16); }
  nin += __shfl_xor((int)nin, 1);
  nout += __shfl_xor((int)nout, 1);
  unsigned dg = nin + nout;
  float inv = 1.0f / (float)(dg > 0 ? dg : 1);
  if (p == 0) { fin[g * 128 + t] = (float)nin * inv; fout[g * 128 + t] = (float)nout * inv; }
  // convert own slice (each thread holds inv in-register; no cross-thread sharing needed)
#pragma unroll
  for (int dir = 0; dir < 2; ++dir) {
    int base = dir * 8192 + t * 64 + p * 32;
#pragma unroll
    for (int k4 = 0; k4 < 8; ++k4) {
      uint4 v = *(const uint4*)&Mi[base + k4 * 4];
      uint4 o;
      o.x = bfpack((float)(v.x & 0xffffu) * inv, (float)(v.x >> 16) * inv);
      o.y = bfpack((float)(v.y & 0xffffu) * inv, (float)(v.y >> 16) * inv);
      o.z = bfpack((float)(v.z & 0xffffu) * inv, (float)(v.z >> 16) * inv);
      o.w = bfpack((float)(v.w & 0xffffu) * inv, (float)(v.w >> 16) * inv);
      *(uint4*)&Mb[(size_t)g * 16384 + base + k4 * 4] = o;
    }
  }
}

// ---------------- prefetch helpers for operand staging (128 rows x 64 shorts -> buf stride 72) ----------------
struct PF { uint4 a, b; };
__device__ __forceinline__ PF pf_load(const unsigned short* __restrict__ srcb, int tid) {
  int row = tid >> 2, c = tid & 3;
  const unsigned short* p = srcb + row * 128 + c * 8;
  PF r;
  r.a = *(const uint4*)p;
  r.b = *(const uint4*)(p + 32);
  return r;
}
__device__ __forceinline__ void pf_store(unsigned short* __restrict__ buf, const PF& r, int tid) {
  int row = tid >> 2, c = tid & 3;
  *(uint4*)(buf + row * 72 + c * 8) = r.a;
  *(uint4*)(buf + row * 72 + (c + 4) * 8) = r.b;
}
// stage order per layer: Min0,Min1,Wn0,Wn1,Mout0,Mout1,Wo0,Wo1,Wr0,Wr1
__device__ __forceinline__ const unsigned short* stage_ptr(int sIdx, const unsigned short* Mg,
                                                           const unsigned short* Wnb, const unsigned short* Wob,
                                                           const unsigned short* Wrb) {
  if (sIdx > 29) sIdx = 29;
  int L = sIdx / 10;
  int r = sIdx - L * 10;
  int half = r & 1;
  int op = r >> 1;
  const unsigned short* base;
  if (op == 0) base = Mg;
  else if (op == 1) base = Wnb + L * 16384;
  else if (op == 2) base = Mg + 16384;
  else if (op == 3) base = Wob + L * 16384;
  else base = Wrb + L * 16384;
  return base + half * 64;
}

// ---------------- fully fused per-graph network ----------------
// grid 256 (1 block/graph), 512 threads (8 waves; wave w owns node rows [16w,16w+16)).
// hT[f][t] bf16 LDS is the layer state. Per layer:
//   accT = hT x (Min as B)  -> AinT (C-layout), shfl-transposed to A-frags -> pre += Ain*Wn^T
//   same for Mout/Wo; Wr-seg A-frags scalar-read from hT; bias-mix + LN + ReLU -> hT.
// Then pool = sT x hT (MFMA), final LN + lin + mask in-block.
__global__ __launch_bounds__(512) void fused_kernel(
    const float* __restrict__ x, const unsigned short* __restrict__ Mb,
    const unsigned short* __restrict__ Wnb, const unsigned short* __restrict__ Wob,
    const unsigned short* __restrict__ Wrb,
    const float* __restrict__ bn, const float* __restrict__ bo,
    const float* __restrict__ fin, const float* __restrict__ fout,
    const float* __restrict__ lng, const float* __restrict__ lnb,
    const float* __restrict__ s,
    const float* __restrict__ flng, const float* __restrict__ flnb,
    const float* __restrict__ linw, const float* __restrict__ bias,
    float* __restrict__ out, float* __restrict__ l1g) {
  __shared__ unsigned short hTs[128 * 136];   // 34.0 KB  h transposed [f][t], pad 136
  __shared__ unsigned short sTs[16 * 136];    //  4.3 KB  s transposed [c][t] bf16
  __shared__ unsigned short buf[128 * 72];    // 18.0 KB  staged operand [n][k-half], pad 72
  __shared__ float colsumS[CCd];
  __shared__ float xcs[CCd], axcs[CCd], msk[CCd];

  const int g = blockIdx.x;
  const int tid = threadIdx.x;
  const int wave = tid >> 6;
  const int lane = tid & 63;
  const int m = lane & 15;
  const int q = lane >> 4;
  const int t0 = wave << 4;
  const unsigned short* Mg = Mb + (size_t)g * 32768;

  int sIdx = 0;
  PF pf = pf_load(stage_ptr(0, Mg, Wnb, Wob, Wrb), tid);   // prefetch Min half0

  // ---- x -> hT (bf16, transposed) ----
  {
    const float4* xg = (const float4*)(x + (size_t)g * 16384);
#pragma unroll
    for (int i = 0; i < 8; ++i) {
      int flat = i * 512 + tid;           // 4096 float4s
      int t = flat >> 5, f0 = (flat & 31) << 2;
      float4 v = xg[flat];
      hTs[(f0 + 0) * 136 + t] = f2bf(v.x);
      hTs[(f0 + 1) * 136 + t] = f2bf(v.y);
      hTs[(f0 + 2) * 136 + t] = f2bf(v.z);
      hTs[(f0 + 3) * 136 + t] = f2bf(v.w);
    }
    int t = tid >> 2, c0 = (tid & 3) << 2;
    float4 v = *(const float4*)(s + (size_t)g * 2048 + t * 16 + c0);
    sTs[(c0 + 0) * 136 + t] = f2bf(v.x);
    sTs[(c0 + 1) * 136 + t] = f2bf(v.y);
    sTs[(c0 + 2) * 136 + t] = f2bf(v.z);
    sTs[(c0 + 3) * 136 + t] = f2bf(v.w);
    if (tid < CCd) {
      float cs = 0.f;
      for (int tt = 0; tt < 128; ++tt) cs += s[(size_t)g * 2048 + tt * 16 + tid];
      colsumS[tid] = cs;
    }
  }

  for (int L = 0; L < LLd; ++L) {
    f32x4 pre[8];
#pragma unroll
    for (int ct = 0; ct < 8; ++ct) pre[ct] = (f32x4){0.f, 0.f, 0.f, 0.f};

    for (int sg = 0; sg < 2; ++sg) {
      // --- M phase: accT[ft] = (Agg^T)[f-tile ft][t-slice of this wave] ---
      f32x4 accT[8];
#pragma unroll
      for (int ft = 0; ft < 8; ++ft) accT[ft] = (f32x4){0.f, 0.f, 0.f, 0.f};
#pragma unroll
      for (int half = 0; half < 2; ++half) {
        __syncthreads();
        pf_store(buf, pf, tid);
        ++sIdx;
        pf = pf_load(stage_ptr(sIdx, Mg, Wnb, Wob, Wrb), tid);
        __syncthreads();
#pragma unroll
        for (int ksl = 0; ksl < 2; ++ksl) {
          const int ksg = half * 2 + ksl;
          short8 bfr = *(const short8*)&buf[(t0 + m) * 72 + ksl * 32 + q * 8];
#pragma unroll
          for (int ft = 0; ft < 8; ++ft) {
            short8 afr = *(const short8*)&hTs[(ft * 16 + m) * 136 + ksg * 32 + q * 8];
            accT[ft] = __builtin_amdgcn_mfma_f32_16x16x32_bf16(afr, bfr, accT[ft], 0, 0, 0);
          }
        }
      }
      // --- main phase: pre += Agg * W^T (A-frags from accT via shfl-transpose) ---
#pragma unroll
      for (int half = 0; half < 2; ++half) {
        __syncthreads();
        pf_store(buf, pf, tid);
        ++sIdx;
        pf = pf_load(stage_ptr(sIdx, Mg, Wnb, Wob, Wrb), tid);
        __syncthreads();
#pragma unroll
        for (int ksl = 0; ksl < 2; ++ksl) {
          const int ksg = half * 2 + ksl;
          // lane (m,q) needs Agg[t0+m][fi=32*ksg+8q+j] = accT value at src lane/reg:
          //   ftile = 2*ksg + (q>>1), fr = (q&1)*8+j, src_lane = (fr>>2)*16 + m, reg = j&3
          f32x4 lo = accT[2 * ksg], hi = accT[2 * ksg + 1];
          short8 afr;
#pragma unroll
          for (int j = 0; j < 8; ++j) {
            int srcl = ((((q & 1) << 1) + (j >> 2)) << 4) + m;
            float ylo = __shfl(lo[j & 3], srcl, 64);
            float yhi = __shfl(hi[j & 3], srcl, 64);
            afr[j] = (short)f2bf((q >> 1) ? yhi : ylo);
          }
#pragma unroll
          for (int ct = 0; ct < 8; ++ct) {
            short8 bfr = *(const short8*)&buf[(ct * 16 + m) * 72 + ksl * 32 + q * 8];
            pre[ct] = __builtin_amdgcn_mfma_f32_16x16x32_bf16(afr, bfr, pre[ct], 0, 0, 0);
          }
        }
      }
    }
    // --- Wr segment: A-frags scalar-read from hT ---
#pragma unroll
    for (int half = 0; half < 2; ++half) {
      __syncthreads();
      pf_store(buf, pf, tid);
      ++sIdx;
      pf = pf_load(stage_ptr(sIdx, Mg, Wnb, Wob, Wrb), tid);
      __syncthreads();
#pragma unroll
      for (int ksl = 0; ksl < 2; ++ksl) {
        const int ksg = half * 2 + ksl;
        short8 afr;
#pragma unroll
        for (int j = 0; j < 8; ++j)
          afr[j] = (short)hTs[(ksg * 32 + q * 8 + j) * 136 + t0 + m];
#pragma unroll
        for (int ct = 0; ct < 8; ++ct) {
          short8 bfr = *(const short8*)&buf[(ct * 16 + m) * 72 + ksl * 32 + q * 8];
          pre[ct] = __builtin_amdgcn_mfma_f32_16x16x32_bf16(afr, bfr, pre[ct], 0, 0, 0);
        }
      }
    }
    // --- epilogue: bias mix + LN + ReLU -> hT (only our wave's t-columns: race-free) ---
    float bnv[8], bov[8], gv[8], bv[8];
#pragma unroll
    for (int ct = 0; ct < 8; ++ct) {
      int c = L * 128 + ct * 16 + m;
      bnv[ct] = bn[c]; bov[ct] = bo[c]; gv[ct] = lng[c]; bv[ct] = lnb[c];
    }
#pragma unroll
    for (int r = 0; r < 4; ++r) {
      const int tl = q * 4 + r;
      const int T = g * 128 + t0 + tl;
      const float fiv = fin[T], fov = fout[T];
      float v[8];
      float sum = 0.f;
#pragma unroll
      for (int ct = 0; ct < 8; ++ct) {
        v[ct] = pre[ct][r] + fiv * bnv[ct] + fov * bov[ct];
        sum += v[ct];
      }
      sum += __shfl_xor(sum, 1); sum += __shfl_xor(sum, 2);
      sum += __shfl_xor(sum, 4); sum += __shfl_xor(sum, 8);
      const float mu = sum * (1.0f / 128.0f);
      float sq = 0.f;
#pragma unroll
      for (int ct = 0; ct < 8; ++ct) { float d = v[ct] - mu; sq += d * d; }
      sq += __shfl_xor(sq, 1); sq += __shfl_xor(sq, 2);
      sq += __shfl_xor(sq, 4); sq += __shfl_xor(sq, 8);
      const float rstd = rsqrtf(sq * (1.0f / 128.0f) + 1e-5f);
#pragma unroll
      for (int ct = 0; ct < 8; ++ct) {
        float o = fmaxf((v[ct] - mu) * rstd * gv[ct] + bv[ct], 0.0f);
        hTs[(ct * 16 + m) * 136 + t0 + tl] = f2bf(o);
      }
    }
  }

  __syncthreads();
  // ---- pool: pooled[c][fo] = sum_t s[t][c]*h[t][fo]; wave w does fo-tile w ----
  f32x4 pl = (f32x4){0.f, 0.f, 0.f, 0.f};
#pragma unroll
  for (int ks = 0; ks < 4; ++ks) {
    short8 a = *(const short8*)&sTs[m * 136 + ks * 32 + q * 8];
    short8 b = *(const short8*)&hTs[(wave * 16 + m) * 136 + ks * 32 + q * 8];
    pl = __builtin_amdgcn_mfma_f32_16x16x32_bf16(a, b, pl, 0, 0, 0);
  }
  float* pooledS = (float*)buf;   // reuse staging buffer (16 x 132 fp32)
#pragma unroll
  for (int r = 0; r < 4; ++r) pooledS[(q * 4 + r) * 132 + wave * 16 + m] = pl[r];
  __syncthreads();

  // ---- final LN + lin + mask (threads 0..255) ----
  if (tid < 256) {
    const int c = tid >> 4;
    const int j0 = (tid & 15) << 3;
    float v[8];
#pragma unroll
    for (int jj = 0; jj < 8; ++jj) v[jj] = pooledS[c * 132 + j0 + jj];
    float sum = 0.f;
#pragma unroll
    for (int jj = 0; jj < 8; ++jj) sum += v[jj];
#pragma unroll
    for (int mk = 1; mk < 16; mk <<= 1) sum += __shfl_xor(sum, mk, 64);
    float mu = sum * (1.0f / 128.0f);
    float sq = 0.f;
#pragma unroll
    for (int jj = 0; jj < 8; ++jj) { float d = v[jj] - mu; sq += d * d; }
#pragma unroll
    for (int mk = 1; mk < 16; mk <<= 1) sq += __shfl_xor(sq, mk, 64);
    float rstd = rsqrtf(sq * (1.0f / 128.0f) + 1e-5f);
    float dot = 0.f;
#pragma unroll
    for (int jj = 0; jj < 8; ++jj) {
      float nv = (v[jj] - mu) * rstd * flng[j0 + jj] + flnb[j0 + jj];
      dot += nv * linw[j0 + jj];
    }
#pragma unroll
    for (int mk = 1; mk < 16; mk <<= 1) dot += __shfl_xor(dot, mk, 64);
    if ((tid & 15) == 0) {
      float cm = (colsumS[c] > 0.f) ? 1.0f : 0.0f;
      float xcv = dot * cm;
      out[257 + g * CCd + c] = xcv;
      xcs[c] = xcv; axcs[c] = fabsf(xcv); msk[c] = cm;
    }
  }
  __syncthreads();
  if (tid == 0) {
    float so = 0.f, sa = 0.f, sd = 0.f;
#pragma unroll
    for (int k = 0; k < CCd; ++k) { so += xcs[k]; sa += axcs[k]; sd += msk[k] + 1e-7f; }
    out[g] = so + bias[0];
    l1g[g] = sa / sd;
  }
}

// ---------------- combine: losses = 0.01*reg + 0.01*mean_g(l1g) ----------------
__global__ __launch_bounds__(256) void combine_kernel(const float* __restrict__ l1g, const float* __restrict__ wsreg,
                                                      float* __restrict__ outp) {
  const int tid = threadIdx.x;
  float s2 = l1g[tid];
#pragma unroll
  for (int mk = 1; mk < 64; mk <<= 1) s2 += __shfl_xor(s2, mk, 64);
  __shared__ float rs2[4];
  if ((tid & 63) == 0) rs2[tid >> 6] = s2;
  __syncthreads();
  if (tid == 0) {
    float l1 = (rs2[0] + rs2[1] + rs2[2] + rs2[3]) * (1.0f / GG);
    outp[0] = 0.01f * wsreg[0] + 0.01f * l1;
  }
}

extern "C" void kernel_launch(void* const* d_in, const int* in_sizes, int n_in,
                              void* d_out, int out_size, void* d_ws, size_t ws_size,
                              hipStream_t stream) {
  (void)in_sizes; (void)n_in; (void)out_size; (void)ws_size;
  const float* x    = (const float*)d_in[0];
  const int*   ei   = (const int*)d_in[1];
  const int*   mask = (const int*)d_in[2];
  const float* s    = (const float*)d_in[3];
  const float* Wn   = (const float*)d_in[5];
  const float* bn   = (const float*)d_in[6];
  const float* Wo   = (const float*)d_in[7];
  const float* bo   = (const float*)d_in[8];
  const float* Wr   = (const float*)d_in[9];
  const float* lng  = (const float*)d_in[10];
  const float* lnb  = (const float*)d_in[11];
  const float* flng = (const float*)d_in[12];
  const float* flnb = (const float*)d_in[13];
  const float* linw = (const float*)d_in[14];
  const float* bias = (const float*)d_in[15];
  float* out = (float*)d_out;

  char* ws = (char*)d_ws;
  size_t off = 0;
  auto alloc = [&](size_t b) { char* p = ws + off; off += (b + 255) & ~(size_t)255; return p; };
  unsigned short* Mbuf = (unsigned short*)alloc((size_t)GG * 2 * 128 * 128 * 2);  // 16.8 MB
  float* fin    = (float*)alloc((size_t)NN * 4);
  float* fout   = (float*)alloc((size_t)NN * 4);
  unsigned short* Wnb = (unsigned short*)alloc((size_t)LLd * HD * HD * 2);
  unsigned short* Wob = (unsigned short*)alloc((size_t)LLd * HD * HD * 2);
  unsigned short* Wrb = (unsigned short*)alloc((size_t)LLd * HD * HD * 2);
  float* l1g    = (float*)alloc((size_t)GG * 4);
  float* wsreg  = (float*)alloc(256);

  const int* srcA = ei;
  const int* tgtA = ei + EE;

  hipMemsetAsync(wsreg, 0, 4, stream);
  convert_w_kernel<<<LLd * HD * HD / (256 * 4), 256, 0, stream>>>(Wn, Wo, Wr, bo,
      (unsigned*)Wnb, (unsigned*)Wob, (unsigned*)Wrb, wsreg);
  build_m_kernel<<<GG, 256, 0, stream>>>(srcA, tgtA, mask, (unsigned*)Mbuf, fin, fout);
  fused_kernel<<<GG, 512, 0, stream>>>(x, Mbuf, Wnb, Wob, Wrb, bn, bo, fin, fout,
                                       lng, lnb, s, flng, flnb, linw, bias, out, l1g);
  combine_kernel<<<1, 256, 0, stream>>>(l1g, wsreg, out + 256);
}